// Round 16
// baseline (275.014 us; speedup 1.0000x reference)
//
#include <hip/hip_runtime.h>

// CRF log-partition forward, MI355X. 64 blocks (1 per sequence) x 64 threads
// (ONE wave -> zero barriers; in-wave DS ordering validated by R13 absmax 0).
// R13 retry with the register-spill fixed: R13 staged all 16 float4 of q at
// once -> peak pressure ~220 -> allocator spilled (VGPR_Count 132, scratch
// hot in L1 -> invisible in FETCH, ~900 cyc/step). Here reads are interleaved
// with consumption in 4 groups (4x ds_read_b128 -> 32 fdot2 -> sched_barrier)
// so peak live regs ~= E(128) + staging(16) + acc(8) + misc(~30) < 256.
// sched_barrier(0) stops the pre-RA scheduler from hoisting all reads.
//
// Lane l owns tags {2l, 2l+1}. E = exp(T) as f16 pairs in 128 named h2 regs
// (EA_m = (E[2m][2l], E[2m+1][2l]); EB_m for col 2l+1). State q packed f16
// pairs in LDS (64 dwords). Renorm: fresh p0 exponent via readfirstlane
// (lane 0 owns tag 0), exact power-of-2, o += eS.
//   q'_j = exp(e_j) * (sum_i q_i E_ij) * 2^(-eS);  out = ln2*(o + log2 sum..)

#define LOG2E 1.4426950408889634f
#define LN2   0.6931471805599453f

typedef float    f2 __attribute__((ext_vector_type(2)));
typedef _Float16 h2 __attribute__((ext_vector_type(2)));

#define PKRTZ(a, b) __builtin_bit_cast(h2, __builtin_amdgcn_cvt_pkrtz((a), (b)))

__global__ __launch_bounds__(64)
__attribute__((amdgpu_waves_per_eu(1, 1)))
void crf_forward(
    const float* __restrict__ emissions,   // [64, 512, 128]
    const float* __restrict__ transitions, // [128, 128]
    const float* __restrict__ start_t,     // [128]
    const float* __restrict__ end_t,       // [128]
    const int*   __restrict__ lengths,     // [64]
    float* __restrict__ out)               // [64]
{
    constexpr int N = 128;
    constexpr int L = 512;
    const int b = blockIdx.x;
    const int l = threadIdx.x;          // lane, owns tags 2l and 2l+1

    __shared__ alignas(16) float pbuf[64];   // packed f16 pairs (q_2m, q_2m+1)

    // ---- one-time: E tile as 128 NAMED h2 registers
    h2 EA_0,  EA_1,  EA_2,  EA_3,  EA_4,  EA_5,  EA_6,  EA_7;
    h2 EA_8,  EA_9,  EA_10, EA_11, EA_12, EA_13, EA_14, EA_15;
    h2 EA_16, EA_17, EA_18, EA_19, EA_20, EA_21, EA_22, EA_23;
    h2 EA_24, EA_25, EA_26, EA_27, EA_28, EA_29, EA_30, EA_31;
    h2 EA_32, EA_33, EA_34, EA_35, EA_36, EA_37, EA_38, EA_39;
    h2 EA_40, EA_41, EA_42, EA_43, EA_44, EA_45, EA_46, EA_47;
    h2 EA_48, EA_49, EA_50, EA_51, EA_52, EA_53, EA_54, EA_55;
    h2 EA_56, EA_57, EA_58, EA_59, EA_60, EA_61, EA_62, EA_63;
    h2 EB_0,  EB_1,  EB_2,  EB_3,  EB_4,  EB_5,  EB_6,  EB_7;
    h2 EB_8,  EB_9,  EB_10, EB_11, EB_12, EB_13, EB_14, EB_15;
    h2 EB_16, EB_17, EB_18, EB_19, EB_20, EB_21, EB_22, EB_23;
    h2 EB_24, EB_25, EB_26, EB_27, EB_28, EB_29, EB_30, EB_31;
    h2 EB_32, EB_33, EB_34, EB_35, EB_36, EB_37, EB_38, EB_39;
    h2 EB_40, EB_41, EB_42, EB_43, EB_44, EB_45, EB_46, EB_47;
    h2 EB_48, EB_49, EB_50, EB_51, EB_52, EB_53, EB_54, EB_55;
    h2 EB_56, EB_57, EB_58, EB_59, EB_60, EB_61, EB_62, EB_63;
    {
#define INIT_M(m)                                                              \
        {                                                                      \
            f2 r0 = *reinterpret_cast<const f2*>(                              \
                transitions + (size_t)(2 * (m)) * N + 2 * l);                  \
            f2 r1 = *reinterpret_cast<const f2*>(                              \
                transitions + (size_t)(2 * (m) + 1) * N + 2 * l);              \
            EA_##m = PKRTZ(__builtin_amdgcn_exp2f(r0.x * LOG2E),               \
                           __builtin_amdgcn_exp2f(r1.x * LOG2E));              \
            EB_##m = PKRTZ(__builtin_amdgcn_exp2f(r0.y * LOG2E),               \
                           __builtin_amdgcn_exp2f(r1.y * LOG2E));              \
        }
        INIT_M(0)  INIT_M(1)  INIT_M(2)  INIT_M(3)
        INIT_M(4)  INIT_M(5)  INIT_M(6)  INIT_M(7)
        INIT_M(8)  INIT_M(9)  INIT_M(10) INIT_M(11)
        INIT_M(12) INIT_M(13) INIT_M(14) INIT_M(15)
        INIT_M(16) INIT_M(17) INIT_M(18) INIT_M(19)
        INIT_M(20) INIT_M(21) INIT_M(22) INIT_M(23)
        INIT_M(24) INIT_M(25) INIT_M(26) INIT_M(27)
        INIT_M(28) INIT_M(29) INIT_M(30) INIT_M(31)
        INIT_M(32) INIT_M(33) INIT_M(34) INIT_M(35)
        INIT_M(36) INIT_M(37) INIT_M(38) INIT_M(39)
        INIT_M(40) INIT_M(41) INIT_M(42) INIT_M(43)
        INIT_M(44) INIT_M(45) INIT_M(46) INIT_M(47)
        INIT_M(48) INIT_M(49) INIT_M(50) INIT_M(51)
        INIT_M(52) INIT_M(53) INIT_M(54) INIT_M(55)
        INIT_M(56) INIT_M(57) INIT_M(58) INIT_M(59)
        INIT_M(60) INIT_M(61) INIT_M(62) INIT_M(63)
#undef INIT_M
    }

    const int len = lengths[b];
    const float* eb = emissions + (size_t)b * L * N;

    // ---- init: p = exp(start + e0), normalized by fresh p0's exponent
    int o = 0;
    float qA, qB;
    {
        f2 st = *reinterpret_cast<const f2*>(start_t + 2 * l);
        f2 e0 = *reinterpret_cast<const f2*>(eb + 2 * l);
        float pA = __builtin_amdgcn_exp2f((st.x + e0.x) * LOG2E);
        float pB = __builtin_amdgcn_exp2f((st.y + e0.y) * LOG2E);
        int u0 = __builtin_amdgcn_readfirstlane(__float_as_int(pA));
        int eS = (int)(((unsigned)u0 >> 23) & 0xFFu) - 127;
        o += eS;
        float sc = __uint_as_float((unsigned)(127 - eS) << 23);
        qA = pA * sc; qB = pB * sc;
        pbuf[l] = __builtin_bit_cast(float, PKRTZ(qA, qB));
    }

    auto clampt = [&](int tt) { return tt < len ? tt : len - 1; };
    auto ldE = [&](int tt) {
        return *reinterpret_cast<const f2*>(eb + (size_t)tt * N + 2 * l);
    };

    auto STEP = [&](f2 ecur) {
        const float4* pv = reinterpret_cast<const float4*>(pbuf);
        float aA0 = 0.f, aA1 = 0.f, aA2 = 0.f, aA3 = 0.f;
        float aB0 = 0.f, aB1 = 0.f, aB2 = 0.f, aB3 = 0.f;
#define DD(m, Qc, ch)                                                          \
        {                                                                      \
            h2 pm = __builtin_bit_cast(h2, Qc);                                \
            aA##ch = __builtin_amdgcn_fdot2(pm, EA_##m, aA##ch, false);        \
            aB##ch = __builtin_amdgcn_fdot2(pm, EB_##m, aB##ch, false);        \
        }
        {   // group 0: q dwords 0..15
            float4 Q0 = pv[0], Q1 = pv[1], Q2 = pv[2], Q3 = pv[3];
            DD(0,  Q0.x, 0) DD(1,  Q0.y, 1) DD(2,  Q0.z, 2) DD(3,  Q0.w, 3)
            DD(4,  Q1.x, 0) DD(5,  Q1.y, 1) DD(6,  Q1.z, 2) DD(7,  Q1.w, 3)
            DD(8,  Q2.x, 0) DD(9,  Q2.y, 1) DD(10, Q2.z, 2) DD(11, Q2.w, 3)
            DD(12, Q3.x, 0) DD(13, Q3.y, 1) DD(14, Q3.z, 2) DD(15, Q3.w, 3)
        }
        __builtin_amdgcn_sched_barrier(0);
        {   // group 1: q dwords 16..31
            float4 Q0 = pv[4], Q1 = pv[5], Q2 = pv[6], Q3 = pv[7];
            DD(16, Q0.x, 0) DD(17, Q0.y, 1) DD(18, Q0.z, 2) DD(19, Q0.w, 3)
            DD(20, Q1.x, 0) DD(21, Q1.y, 1) DD(22, Q1.z, 2) DD(23, Q1.w, 3)
            DD(24, Q2.x, 0) DD(25, Q2.y, 1) DD(26, Q2.z, 2) DD(27, Q2.w, 3)
            DD(28, Q3.x, 0) DD(29, Q3.y, 1) DD(30, Q3.z, 2) DD(31, Q3.w, 3)
        }
        __builtin_amdgcn_sched_barrier(0);
        {   // group 2: q dwords 32..47
            float4 Q0 = pv[8], Q1 = pv[9], Q2 = pv[10], Q3 = pv[11];
            DD(32, Q0.x, 0) DD(33, Q0.y, 1) DD(34, Q0.z, 2) DD(35, Q0.w, 3)
            DD(36, Q1.x, 0) DD(37, Q1.y, 1) DD(38, Q1.z, 2) DD(39, Q1.w, 3)
            DD(40, Q2.x, 0) DD(41, Q2.y, 1) DD(42, Q2.z, 2) DD(43, Q2.w, 3)
            DD(44, Q3.x, 0) DD(45, Q3.y, 1) DD(46, Q3.z, 2) DD(47, Q3.w, 3)
        }
        __builtin_amdgcn_sched_barrier(0);
        {   // group 3: q dwords 48..63
            float4 Q0 = pv[12], Q1 = pv[13], Q2 = pv[14], Q3 = pv[15];
            DD(48, Q0.x, 0) DD(49, Q0.y, 1) DD(50, Q0.z, 2) DD(51, Q0.w, 3)
            DD(52, Q1.x, 0) DD(53, Q1.y, 1) DD(54, Q1.z, 2) DD(55, Q1.w, 3)
            DD(56, Q2.x, 0) DD(57, Q2.y, 1) DD(58, Q2.z, 2) DD(59, Q2.w, 3)
            DD(60, Q3.x, 0) DD(61, Q3.y, 1) DD(62, Q3.z, 2) DD(63, Q3.w, 3)
        }
#undef DD
        float dA = (aA0 + aA1) + (aA2 + aA3);
        float dB = (aB0 + aB1) + (aB2 + aB3);

        float esA = __builtin_amdgcn_exp2f(ecur.x * LOG2E);
        float esB = __builtin_amdgcn_exp2f(ecur.y * LOG2E);
        float pA = esA * dA;
        float pB = esB * dB;

        // renormalize by the FRESH p0's exponent (lane 0 owns tag 0):
        // stored p0 stays in [1,2); spread bounded -- safe in f16 (R13: absmax 0)
        int u0 = __builtin_amdgcn_readfirstlane(__float_as_int(pA));
        int eS = (int)(((unsigned)u0 >> 23) & 0xFFu) - 127;
        o += eS;
        float sc = __uint_as_float((unsigned)(127 - eS) << 23);
        qA = pA * sc; qB = pB * sc;
        pbuf[l] = __builtin_bit_cast(float, PKRTZ(qA, qB));
        // no barrier: in-wave DS ordering covers write -> next-step reads
    };

    // ---- main loop: distance-4 emission prefetch, manual 4-way unroll
    f2 ra = ldE(clampt(1));
    f2 rb = ldE(clampt(2));
    f2 rc = ldE(clampt(3));
    f2 rd = ldE(clampt(4));

    int t = 1;
    while (t < len) {
        STEP(ra); ra = ldE(clampt(t + 4)); ++t; if (t >= len) break;
        STEP(rb); rb = ldE(clampt(t + 4)); ++t; if (t >= len) break;
        STEP(rc); rc = ldE(clampt(t + 4)); ++t; if (t >= len) break;
        STEP(rd); rd = ldE(clampt(t + 4)); ++t;
    }

    // ---- finalize: out[b] = ln2 * (o + log2(sum_j q_j * exp(end_j)))
    {
        f2 ef = *reinterpret_cast<const f2*>(end_t + 2 * l);
        float vend = qA * __builtin_amdgcn_exp2f(ef.x * LOG2E)
                   + qB * __builtin_amdgcn_exp2f(ef.y * LOG2E);
        #pragma unroll
        for (int m = 1; m < 64; m <<= 1) vend += __shfl_xor(vend, m);
        if (l == 0)
            out[b] = LN2 * ((float)o + __builtin_amdgcn_logf(vend));
    }
}

extern "C" void kernel_launch(void* const* d_in, const int* in_sizes, int n_in,
                              void* d_out, int out_size, void* d_ws, size_t ws_size,
                              hipStream_t stream) {
    const float* emissions   = (const float*)d_in[0];
    const float* transitions = (const float*)d_in[1];
    const float* start_t     = (const float*)d_in[2];
    const float* end_t       = (const float*)d_in[3];
    const int*   lengths     = (const int*)d_in[4];
    float* out = (float*)d_out;

    crf_forward<<<dim3(64), dim3(64), 0, stream>>>(
        emissions, transitions, start_t, end_t, lengths, out);
}